// Round 2
// baseline (290.019 us; speedup 1.0000x reference)
//
#include <hip/hip_runtime.h>
#include <hip/hip_bf16.h>

// BERT_SCL: loss = 0.9 * supcon(cls_emb, labels) + 0.1 * CE(pooled@W.T + b, labels)
// d_out[0] = loss, d_out[1..57344] = logits (8192 x 7, f32)
//
// e8 = fp8_e4m3(row-normalized cls * 1/sqrt(TEMP)); en = bf16 of the same.
// S_ij = e8_i . e8_j <= M = 1/TEMP -> fixed-max logsumexp. possum_i =
// en_i.T_{l_i} - ||en_i||^2 (positive mask linear in S) -> big kernel does
// ONLY exp-sums, via MX-scaled fp8 MFMA (16x16x128, unit scales 0x7F).
// S symmetric -> tiles bi <= bj (2080); off-diag tiles emit row AND col sums.
// Supertile swizzle (8x8) keeps co-resident panels in per-XCD L2.
//
// Ledger: r2 single-address atomics ~100us; r3 supertile fixes L2 thrash;
// r4 forced waves/EU -> acc spill = never force; r5 <1blk/CU latency-bound;
// r6 k_scl staging/latency-bound; r7 scaled MFMA + rotate swizzle + dual
// e8+bf16; r8 node count weak lever; r9 dbuf+raw-barrier 81->64.5us but
// still ~2650cy/kc vs ~1100 floor: per-kc vmcnt(0)+s_barrier makes every
// HBM/L3 straggler stall all 4 waves, and 64KB LDS caps 2 blk/CU.
// r10 (this): e8 panels L2-FIT (supertile set 1.57MB < 4MB/XCD; FETCH only
// 25MB = 4x array) -> drop LDS staging entirely (Common-mistake #7). MFMA
// frags read DIRECT from global (same 128B/row coalescing as the old stage
// loads), zero barriers, zero LDS, zero bank conflicts; waves wait only on
// their own loads (compiler-counted vmcnt over fully unrolled 6-kc loop);
// occupancy VGPR-capped ~3 blk/CU instead of LDS-capped 2.

#define B_N 8192
#define D_K 768
#define NLAB 7
#define MBOUND 3.3333333333333335f /* 1/TEMP */
#define RTINV 1.8257418583505538f  /* 1/sqrt(TEMP) */

typedef float f32x4 __attribute__((ext_vector_type(4)));
typedef int i32x8 __attribute__((ext_vector_type(8)));

__device__ __forceinline__ float bf16u_to_f(unsigned short u) {
  return __uint_as_float(((unsigned int)u) << 16);
}

// exact fp8 e4m3fn -> f32 decode (fallback paths only)
__device__ __forceinline__ float dec8(unsigned int b) {
  unsigned int s = (b >> 7) & 1u, e = (b >> 3) & 15u, m = b & 7u;
  float fn = __uint_as_float((s << 31) | ((e + 120u) << 23) | (m << 20));
  float fs = (s ? -1.f : 1.f) * (float)m * 0.001953125f;
  return e ? fn : fs;
}

// ---- node 1: k_prep = zero accumulators + normalize -> {fp8, bf16} + logits + CE ----
template <int WBF>
__global__ __launch_bounds__(256) void k_prep(
    const float* __restrict__ cls, const float* __restrict__ pooled,
    const int* __restrict__ labels, const float* __restrict__ W,
    const float* __restrict__ bias, unsigned char* __restrict__ e8,
    unsigned short* __restrict__ en, float* __restrict__ logits_out,
    float* __restrict__ celoss, int* __restrict__ zr) {
  if (blockIdx.x == 0)
    for (int t = threadIdx.x; t < 9280; t += 256) zr[t] = 0;

  int wv = threadIdx.x >> 6, lane = threadIdx.x & 63;
  int row = blockIdx.x * 4 + wv;

  // --- normalize + quantize ---
  const float4* src = (const float4*)(cls + (size_t)row * D_K);
  float4 x[3];
  float ss = 0.f;
#pragma unroll
  for (int j = 0; j < 3; ++j) {
    x[j] = src[j * 64 + lane];
    ss += x[j].x * x[j].x + x[j].y * x[j].y + x[j].z * x[j].z + x[j].w * x[j].w;
  }
#pragma unroll
  for (int m = 1; m < 64; m <<= 1) ss += __shfl_xor(ss, m);
  float sc = rsqrtf(ss) * RTINV;
  int* d8 = (int*)(e8 + (size_t)row * D_K);
  ushort4* db = (ushort4*)(en + (size_t)row * D_K);
#pragma unroll
  for (int j = 0; j < 3; ++j) {
    int w32 = __builtin_amdgcn_cvt_pk_fp8_f32(x[j].x * sc, x[j].y * sc, 0, false);
    w32 = __builtin_amdgcn_cvt_pk_fp8_f32(x[j].z * sc, x[j].w * sc, w32, true);
    d8[j * 64 + lane] = w32;
    if (WBF) {
      const float* xv = reinterpret_cast<const float*>(&x[j]);
      ushort4 o;
      unsigned short* ov = reinterpret_cast<unsigned short*>(&o);
#pragma unroll
      for (int k = 0; k < 4; ++k) {
        __hip_bfloat16 h = __float2bfloat16(xv[k] * sc);
        ov[k] = *reinterpret_cast<unsigned short*>(&h);
      }
      db[j * 64 + lane] = o;
    }
  }

  // --- logits + CE ---
  const float4* p4 = (const float4*)(pooled + (size_t)row * D_K);
  float acc[NLAB];
#pragma unroll
  for (int c = 0; c < NLAB; ++c) acc[c] = 0.f;
#pragma unroll
  for (int j = 0; j < 3; ++j) {
    float4 xx = p4[j * 64 + lane];
#pragma unroll
    for (int c = 0; c < NLAB; ++c) {
      float4 w = ((const float4*)(W + c * D_K))[j * 64 + lane];
      acc[c] += xx.x * w.x + xx.y * w.y + xx.z * w.z + xx.w * w.w;
    }
  }
#pragma unroll
  for (int c = 0; c < NLAB; ++c)
#pragma unroll
    for (int m = 1; m < 64; m <<= 1) acc[c] += __shfl_xor(acc[c], m);
  if (lane == 0) {
    float l[NLAB], mx = -1e30f;
#pragma unroll
    for (int c = 0; c < NLAB; ++c) { l[c] = acc[c] + bias[c]; mx = fmaxf(mx, l[c]); }
    float se = 0.f;
#pragma unroll
    for (int c = 0; c < NLAB; ++c) se += __expf(l[c] - mx);
    float lse = mx + __logf(se);
    celoss[row] = lse - l[labels[row]];
    float* o = logits_out + (size_t)row * NLAB;
#pragma unroll
    for (int c = 0; c < NLAB; ++c) o[c] = l[c];
  }
}

// ---- node 2: class-sum stage A (direct stores) + hist ----
// 128 blocks: block g = (slab g>>1, dim-half g&1). Each block sums 384 dims of
// its slab's 128 rows; same partial layout as before (bitwise-identical sums,
// rows accumulated in the same order per dim). hist computed by wave 3 of the
// half==0 blocks only. M=0: read bf16 en; M=1: read fp8 e8 (fallback).
template <int M>
__global__ __launch_bounds__(256) void k_classumA(
    const unsigned short* __restrict__ en, const unsigned char* __restrict__ e8,
    const int* __restrict__ labels, float* __restrict__ partial,
    int* __restrict__ hist) {
  int g = blockIdx.x, t = threadIdx.x;
  int slab = g >> 1, half = g & 1;
  int r0 = slab * 128;
  int dbase = half * 384;
  if (t < 96) {
    float acc[NLAB][4];
#pragma unroll
    for (int c = 0; c < NLAB; ++c)
#pragma unroll
      for (int k = 0; k < 4; ++k) acc[c][k] = 0.f;
    for (int r = 0; r < 128; r += 4) {
      int lab[4];
      float xv[4][4];
#pragma unroll
      for (int q = 0; q < 4; ++q) {
        int row = r0 + r + q;
        lab[q] = labels[row];
        if (M == 0) {
          ushort4 u = *(const ushort4*)(en + (size_t)row * D_K + dbase + t * 4);
          xv[q][0] = bf16u_to_f(u.x); xv[q][1] = bf16u_to_f(u.y);
          xv[q][2] = bf16u_to_f(u.z); xv[q][3] = bf16u_to_f(u.w);
        } else {
          uchar4 u = *(const uchar4*)(e8 + (size_t)row * D_K + dbase + t * 4);
          xv[q][0] = dec8(u.x); xv[q][1] = dec8(u.y);
          xv[q][2] = dec8(u.z); xv[q][3] = dec8(u.w);
        }
      }
#pragma unroll
      for (int q = 0; q < 4; ++q)
#pragma unroll
        for (int c = 0; c < NLAB; ++c) {
          bool m = (lab[q] == c);
          acc[c][0] += m ? xv[q][0] : 0.f;
          acc[c][1] += m ? xv[q][1] : 0.f;
          acc[c][2] += m ? xv[q][2] : 0.f;
          acc[c][3] += m ? xv[q][3] : 0.f;
        }
    }
    float* dst = partial + (size_t)slab * (NLAB * D_K) + dbase;
#pragma unroll
    for (int c = 0; c < NLAB; ++c) {
      float4 v = {acc[c][0], acc[c][1], acc[c][2], acc[c][3]};
      *(float4*)(dst + c * D_K + t * 4) = v;
    }
  } else if (t >= 192 && half == 0) {
    int lane = t - 192;
    int cnt[NLAB];
#pragma unroll
    for (int c = 0; c < NLAB; ++c) cnt[c] = 0;
#pragma unroll
    for (int q = 0; q < 2; ++q) {
      int lab = labels[r0 + q * 64 + lane];
#pragma unroll
      for (int c = 0; c < NLAB; ++c) cnt[c] += (lab == c);
    }
#pragma unroll
    for (int c = 0; c < NLAB; ++c)
#pragma unroll
      for (int m = 1; m < 64; m <<= 1) cnt[c] += __shfl_xor(cnt[c], m);
    if (lane == 0)
#pragma unroll
      for (int c = 0; c < NLAB; ++c) atomicAdd(&hist[c], cnt[c]);
  }
}

// ---- node 3: exp-sum S-tiles via MX-scaled fp8 MFMA (16x16x128), upper-tri ----
// Blocks >= 2080 run class-sum stage B (only needs node-2 output).
// NO LDS: fragments load DIRECT from global. Per wave-load: 16 rows x 128B
// contiguous (4 quads x 32B per row) = same coalescing as the old stage.
// Supertile panel set (16 x 98KB = 1.57MB) is L2-resident per XCD; within a
// block, wave pairs re-read each A/B half -> mostly L1/L2 hits. No barriers,
// no vmcnt drains: each wave waits only its own loads; full 6-kc unroll lets
// the compiler software-pipeline with counted vmcnt.
__global__ __launch_bounds__(256) void k_scl(const unsigned char* __restrict__ e8,
                                             float* __restrict__ rse,
                                             const float* __restrict__ partial,
                                             float* __restrict__ T) {
  if (blockIdx.x >= 2080) {  // classumB role: T[idx] = sum_g partial[g][idx]
    int idx = (int)(blockIdx.x - 2080) * 256 + threadIdx.x;  // < 5376
    float v = 0.f;
    for (int g = 0; g < 64; ++g) v += partial[(size_t)g * (NLAB * D_K) + idx];
    T[idx] = v;
    return;
  }

  // supertile decode: 8x8-block supertiles over the triangle
  int rem = blockIdx.x;
  int BI = 0, BJ = 0;
  for (;;) {
    int sz = (BI == BJ) ? 36 : 64;
    if (rem < sz) break;
    rem -= sz;
    if (++BJ == 8) { ++BI; BJ = BI; }
  }
  int bi, bj;
  if (BI == BJ) {
    int r = 0, w = 8;
    while (rem >= w) { rem -= w; ++r; --w; }
    bi = BI * 8 + r;
    bj = BJ * 8 + r + rem;
  } else {
    bi = BI * 8 + (rem >> 3);
    bj = BJ * 8 + (rem & 7);
  }

  const int i0 = bi * 128, j0 = bj * 128;
  const int tid = threadIdx.x, wv = tid >> 6, lane = tid & 63;
  const int quad = lane >> 4, cix = lane & 15;
  const int rowTile = 64 * (wv >> 1), colTile = 64 * (wv & 1);

  // per-lane global fragment bases: lane (quad,cix) of subtile mt/nt holds
  // row (base + 16*mt + cix), k-bytes [quad*32, quad*32+32)
  const unsigned char* arow[4];
  const unsigned char* brow[4];
#pragma unroll
  for (int mt = 0; mt < 4; ++mt) {
    arow[mt] = e8 + (size_t)(i0 + rowTile + 16 * mt + cix) * D_K + quad * 32;
    brow[mt] = e8 + (size_t)(j0 + colTile + 16 * mt + cix) * D_K + quad * 32;
  }

  f32x4 acc[4][4] = {};

#pragma unroll
  for (int kc = 0; kc < 6; ++kc) {
    i32x8 aF[4];
#pragma unroll
    for (int mt = 0; mt < 4; ++mt) {
      int4 lo = *(const int4*)(arow[mt] + kc * 128);
      int4 hi = *(const int4*)(arow[mt] + kc * 128 + 16);
      aF[mt][0] = lo.x; aF[mt][1] = lo.y; aF[mt][2] = lo.z; aF[mt][3] = lo.w;
      aF[mt][4] = hi.x; aF[mt][5] = hi.y; aF[mt][6] = hi.z; aF[mt][7] = hi.w;
    }
#pragma unroll
    for (int nt = 0; nt < 4; ++nt) {  // bF streamed: 1 live frag
      int4 lo = *(const int4*)(brow[nt] + kc * 128);
      int4 hi = *(const int4*)(brow[nt] + kc * 128 + 16);
      i32x8 bF;
      bF[0] = lo.x; bF[1] = lo.y; bF[2] = lo.z; bF[3] = lo.w;
      bF[4] = hi.x; bF[5] = hi.y; bF[6] = hi.z; bF[7] = hi.w;
#pragma unroll
      for (int mt = 0; mt < 4; ++mt)
        acc[mt][nt] = __builtin_amdgcn_mfma_scale_f32_16x16x128_f8f6f4(
            aF[mt], bF, acc[mt][nt], 0, 0, 0, 127, 0, 127);  // fp8 fmt, scale=1.0
    }
  }

  // ---- epilogue: exp-sums only (16x16 C/D: col=lane&15, row=quad*4+rg) ----
  if (bi != bj) {
    float ce_col[4] = {0.f, 0.f, 0.f, 0.f};
#pragma unroll
    for (int mt = 0; mt < 4; ++mt) {
      int rowbase = i0 + rowTile + 16 * mt + quad * 4;
      float rs_e[4] = {0.f, 0.f, 0.f, 0.f};
#pragma unroll
      for (int nt = 0; nt < 4; ++nt) {
#pragma unroll
        for (int rg = 0; rg < 4; ++rg) {
          float e = __expf(acc[mt][nt][rg] - MBOUND);
          rs_e[rg] += e;
          ce_col[nt] += e;
        }
      }
#pragma unroll
      for (int rg = 0; rg < 4; ++rg)
#pragma unroll
        for (int m = 1; m <= 8; m <<= 1) rs_e[rg] += __shfl_xor(rs_e[rg], m);
      if (cix == 0)
#pragma unroll
        for (int rg = 0; rg < 4; ++rg) atomicAdd(&rse[rowbase + rg], rs_e[rg]);
    }
#pragma unroll
    for (int nt = 0; nt < 4; ++nt) {
      ce_col[nt] += __shfl_xor(ce_col[nt], 16);
      ce_col[nt] += __shfl_xor(ce_col[nt], 32);
    }
    if (quad == 0)
#pragma unroll
      for (int nt = 0; nt < 4; ++nt)
        atomicAdd(&rse[j0 + colTile + 16 * nt + cix], ce_col[nt]);
  } else {
#pragma unroll
    for (int mt = 0; mt < 4; ++mt) {
      int rowbase = i0 + rowTile + 16 * mt + quad * 4;
      float rs_e[4] = {0.f, 0.f, 0.f, 0.f};
#pragma unroll
      for (int nt = 0; nt < 4; ++nt) {
        int gcol = j0 + colTile + 16 * nt + cix;
#pragma unroll
        for (int rg = 0; rg < 4; ++rg) {
          bool dg = (rowbase + rg) == gcol;
          rs_e[rg] += dg ? 0.f : __expf(acc[mt][nt][rg] - MBOUND);
        }
      }
#pragma unroll
      for (int rg = 0; rg < 4; ++rg)
#pragma unroll
        for (int m = 1; m <= 8; m <<= 1) rs_e[rg] += __shfl_xor(rs_e[rg], m);
      if (cix == 0)
#pragma unroll
        for (int rg = 0; rg < 4; ++rg) atomicAdd(&rse[rowbase + rg], rs_e[rg]);
    }
  }
}

// ---- node 4: per-row combine + last-block final reduce ----
template <int M>
__global__ __launch_bounds__(256) void k_rowfinal(
    const float* __restrict__ rse, const unsigned short* __restrict__ en,
    const unsigned char* __restrict__ e8, const float* __restrict__ T,
    const int* __restrict__ labels, const int* __restrict__ hist,
    const float* __restrict__ celoss, float* __restrict__ contrP,
    int* __restrict__ done_count, float* __restrict__ out) {
  __shared__ float part[4];
  int wv = threadIdx.x >> 6, lane = threadIdx.x & 63;
  int row = blockIdx.x * 4 + wv;
  int l = labels[row];
  const float4* t4 = (const float4*)(T + (size_t)l * D_K);
  float pd = 0.f, sd = 0.f;
#pragma unroll
  for (int j = 0; j < 3; ++j) {
    float a0, a1, a2, a3;
    if (M == 0) {
      ushort4 u = ((const ushort4*)(en + (size_t)row * D_K))[j * 64 + lane];
      a0 = bf16u_to_f(u.x); a1 = bf16u_to_f(u.y);
      a2 = bf16u_to_f(u.z); a3 = bf16u_to_f(u.w);
    } else {
      uint u = ((const uint*)(e8 + (size_t)row * D_K))[j * 64 + lane];
      a0 = dec8(u & 0xff); a1 = dec8((u >> 8) & 0xff);
      a2 = dec8((u >> 16) & 0xff); a3 = dec8(u >> 24);
    }
    float4 t = t4[j * 64 + lane];
    pd += a0 * t.x + a1 * t.y + a2 * t.z + a3 * t.w;
    sd += a0 * a0 + a1 * a1 + a2 * a2 + a3 * a3;
  }
#pragma unroll
  for (int m = 1; m < 64; m <<= 1) {
    pd += __shfl_xor(pd, m);
    sd += __shfl_xor(sd, m);
  }
  if (lane == 0) {
    int ni = hist[l] - 1;
    float per = 0.f;
    if (ni > 0) per = MBOUND + __logf(rse[row]) - (pd - sd) / (float)ni;
    part[wv] = 0.9f * per + (0.1f / (float)B_N) * celoss[row];
  }
  __syncthreads();
  if (threadIdx.x == 0) {
    float v = part[0] + part[1] + part[2] + part[3];
    atomicAdd(&contrP[(blockIdx.x & 63) * 16], v);
    __threadfence();
    int n = atomicAdd(done_count, 1);
    if (n == (int)gridDim.x - 1) {
      float s = 0.f;
      for (int i = 0; i < 64; ++i)
        s += __hip_atomic_load(&contrP[i * 16], __ATOMIC_RELAXED,
                               __HIP_MEMORY_SCOPE_AGENT);
      out[0] = s;
    }
  }
}

extern "C" void kernel_launch(void* const* d_in, const int* in_sizes, int n_in,
                              void* d_out, int out_size, void* d_ws, size_t ws_size,
                              hipStream_t stream) {
  const float* cls    = (const float*)d_in[0];
  const float* pooled = (const float*)d_in[1];
  const int*   labels = (const int*)d_in[2];
  const float* W      = (const float*)d_in[3];
  const float* bias   = (const float*)d_in[4];
  float* out = (float*)d_out;

  char* ws = (char*)d_ws;
  unsigned char* e8 = (unsigned char*)ws;          // 6291456 B
  const size_t EN_B = (size_t)B_N * D_K * 2;       // 12582912
  const size_t E8_B = (size_t)B_N * D_K;           // 6291456
  size_t need_big = E8_B + EN_B + 98304 + 64 * (size_t)(NLAB * D_K) * 4;
  bool big = ws_size >= need_big;                  // 20348928 B
  unsigned short* en = (unsigned short*)(ws + E8_B);
  size_t off = big ? (E8_B + EN_B) : E8_B;
  float* rse     = (float*)(ws + off);             // +0      (32768) [zeroed]
  int*   hist    = (int*)(ws + off + 32768);       // +32768  (128)   [zeroed]
  int*   done    = (int*)(ws + off + 32896);       // +32896  (128)   [zeroed]
  float* contrP  = (float*)(ws + off + 33024);     // +33024  (4096)  [zeroed]
  float* T       = (float*)(ws + off + 37120);     // +37120  (21504, fully written)
  float* celoss  = (float*)(ws + off + 58624);     // +58624  (32768, fully written)
  float* partial = (float*)(ws + off + 98304);     // +98304  (1376256, fully written)
  int*   zr      = (int*)(ws + off);               // 9280 ints = rse..contrP

  if (big)
    k_prep<1><<<B_N / 4, 256, 0, stream>>>(cls, pooled, labels, W, bias, e8, en,
                                           out + 1, celoss, zr);
  else
    k_prep<0><<<B_N / 4, 256, 0, stream>>>(cls, pooled, labels, W, bias, e8, en,
                                           out + 1, celoss, zr);
  if (big)
    k_classumA<0><<<128, 256, 0, stream>>>(en, e8, labels, partial, hist);
  else
    k_classumA<1><<<128, 256, 0, stream>>>(en, e8, labels, partial, hist);
  k_scl<<<2101, 256, 0, stream>>>(e8, rse, partial, T);  // +21 classumB blocks
  if (big)
    k_rowfinal<0><<<B_N / 4, 256, 0, stream>>>(rse, en, e8, T, labels, hist,
                                               celoss, contrP, done, out);
  else
    k_rowfinal<1><<<B_N / 4, 256, 0, stream>>>(rse, en, e8, T, labels, hist,
                                               celoss, contrP, done, out);
}

// Round 3
// 245.403 us; speedup vs baseline: 1.1818x; 1.1818x over previous
//
#include <hip/hip_runtime.h>
#include <hip/hip_bf16.h>

// BERT_SCL: loss = 0.9 * supcon(cls_emb, labels) + 0.1 * CE(pooled@W.T + b, labels)
// d_out[0] = loss, d_out[1..57344] = logits (8192 x 7, f32)
//
// e8 = fp8_e4m3(row-normalized cls * 1/sqrt(TEMP)); en = bf16 of the same.
// S_ij = e8_i . e8_j <= M = 1/TEMP -> fixed-max logsumexp. possum_i =
// en_i.T_{l_i} - ||en_i||^2 (positive mask linear in S) -> big kernel does
// ONLY exp-sums, via MX-scaled fp8 MFMA (16x16x128, unit scales 0x7F).
// S symmetric -> tiles bi <= bj (2080); off-diag tiles emit row AND col sums.
// Supertile swizzle (8x8) keeps co-resident panels in per-XCD L2.
//
// Ledger: r2 single-address atomics ~100us; r3 supertile fixes L2 thrash;
// r4 forced waves/EU -> acc spill = never force; r5 <1blk/CU latency-bound;
// r6 k_scl staging/latency-bound; r7 scaled MFMA + rotate swizzle + dual
// e8+bf16; r8 node count weak lever (~120us residual = launch/drain);
// r9 dbuf+raw-barrier 81->64.5us (vmcnt(0) cover only 1 phase; 2 blk/CU
// phase-align and stack LDS/MFMA bursts); r10 direct-from-L2 FAILED 129us:
// strided frag gathers = 16 txn/instr, request-rate bound (HBM GB/s halved,
// same bytes) -> LDS staging is mandatory for fragment coalescing.
// r11 (this): ring-3 LDS (96KB, 1 blk/CU) + counted vmcnt(8) (T4): prefetch
// kc+2 each iter -> 2 compute-phases of cover (~1800cy vs 585 need), never
// drain to 0 mid-loop; solo block = no co-resident pipe contention (MFMA
// 553/kc solo, LDS 770/kc solo). Target k_scl ~32-42us.

#define B_N 8192
#define D_K 768
#define NLAB 7
#define MBOUND 3.3333333333333335f /* 1/TEMP */
#define RTINV 1.8257418583505538f  /* 1/sqrt(TEMP) */

typedef float f32x4 __attribute__((ext_vector_type(4)));
typedef int i32x8 __attribute__((ext_vector_type(8)));

__device__ __forceinline__ void gl2lds16(const void* g, void* l) {
  __builtin_amdgcn_global_load_lds(
      (const __attribute__((address_space(1))) void*)g,
      (__attribute__((address_space(3))) void*)l, 16, 0, 0);
}

__device__ __forceinline__ float bf16u_to_f(unsigned short u) {
  return __uint_as_float(((unsigned int)u) << 16);
}

// exact fp8 e4m3fn -> f32 decode (fallback paths only)
__device__ __forceinline__ float dec8(unsigned int b) {
  unsigned int s = (b >> 7) & 1u, e = (b >> 3) & 15u, m = b & 7u;
  float fn = __uint_as_float((s << 31) | ((e + 120u) << 23) | (m << 20));
  float fs = (s ? -1.f : 1.f) * (float)m * 0.001953125f;
  return e ? fn : fs;
}

// ---- node 1: k_prep = zero accumulators + normalize -> {fp8, bf16} + logits + CE ----
template <int WBF>
__global__ __launch_bounds__(256) void k_prep(
    const float* __restrict__ cls, const float* __restrict__ pooled,
    const int* __restrict__ labels, const float* __restrict__ W,
    const float* __restrict__ bias, unsigned char* __restrict__ e8,
    unsigned short* __restrict__ en, float* __restrict__ logits_out,
    float* __restrict__ celoss, int* __restrict__ zr) {
  if (blockIdx.x == 0)
    for (int t = threadIdx.x; t < 9280; t += 256) zr[t] = 0;

  int wv = threadIdx.x >> 6, lane = threadIdx.x & 63;
  int row = blockIdx.x * 4 + wv;

  // --- normalize + quantize ---
  const float4* src = (const float4*)(cls + (size_t)row * D_K);
  float4 x[3];
  float ss = 0.f;
#pragma unroll
  for (int j = 0; j < 3; ++j) {
    x[j] = src[j * 64 + lane];
    ss += x[j].x * x[j].x + x[j].y * x[j].y + x[j].z * x[j].z + x[j].w * x[j].w;
  }
#pragma unroll
  for (int m = 1; m < 64; m <<= 1) ss += __shfl_xor(ss, m);
  float sc = rsqrtf(ss) * RTINV;
  int* d8 = (int*)(e8 + (size_t)row * D_K);
  ushort4* db = (ushort4*)(en + (size_t)row * D_K);
#pragma unroll
  for (int j = 0; j < 3; ++j) {
    int w32 = __builtin_amdgcn_cvt_pk_fp8_f32(x[j].x * sc, x[j].y * sc, 0, false);
    w32 = __builtin_amdgcn_cvt_pk_fp8_f32(x[j].z * sc, x[j].w * sc, w32, true);
    d8[j * 64 + lane] = w32;
    if (WBF) {
      const float* xv = reinterpret_cast<const float*>(&x[j]);
      ushort4 o;
      unsigned short* ov = reinterpret_cast<unsigned short*>(&o);
#pragma unroll
      for (int k = 0; k < 4; ++k) {
        __hip_bfloat16 h = __float2bfloat16(xv[k] * sc);
        ov[k] = *reinterpret_cast<unsigned short*>(&h);
      }
      db[j * 64 + lane] = o;
    }
  }

  // --- logits + CE ---
  const float4* p4 = (const float4*)(pooled + (size_t)row * D_K);
  float acc[NLAB];
#pragma unroll
  for (int c = 0; c < NLAB; ++c) acc[c] = 0.f;
#pragma unroll
  for (int j = 0; j < 3; ++j) {
    float4 xx = p4[j * 64 + lane];
#pragma unroll
    for (int c = 0; c < NLAB; ++c) {
      float4 w = ((const float4*)(W + c * D_K))[j * 64 + lane];
      acc[c] += xx.x * w.x + xx.y * w.y + xx.z * w.z + xx.w * w.w;
    }
  }
#pragma unroll
  for (int c = 0; c < NLAB; ++c)
#pragma unroll
    for (int m = 1; m < 64; m <<= 1) acc[c] += __shfl_xor(acc[c], m);
  if (lane == 0) {
    float l[NLAB], mx = -1e30f;
#pragma unroll
    for (int c = 0; c < NLAB; ++c) { l[c] = acc[c] + bias[c]; mx = fmaxf(mx, l[c]); }
    float se = 0.f;
#pragma unroll
    for (int c = 0; c < NLAB; ++c) se += __expf(l[c] - mx);
    float lse = mx + __logf(se);
    celoss[row] = lse - l[labels[row]];
    float* o = logits_out + (size_t)row * NLAB;
#pragma unroll
    for (int c = 0; c < NLAB; ++c) o[c] = l[c];
  }
}

// ---- node 2: class-sum stage A (direct stores) + hist ----
// 128 blocks: block g = (slab g>>1, dim-half g&1). Each block sums 384 dims of
// its slab's 128 rows; same partial layout as before (bitwise-identical sums,
// rows accumulated in the same order per dim). hist computed by wave 3 of the
// half==0 blocks only. M=0: read bf16 en; M=1: read fp8 e8 (fallback).
template <int M>
__global__ __launch_bounds__(256) void k_classumA(
    const unsigned short* __restrict__ en, const unsigned char* __restrict__ e8,
    const int* __restrict__ labels, float* __restrict__ partial,
    int* __restrict__ hist) {
  int g = blockIdx.x, t = threadIdx.x;
  int slab = g >> 1, half = g & 1;
  int r0 = slab * 128;
  int dbase = half * 384;
  if (t < 96) {
    float acc[NLAB][4];
#pragma unroll
    for (int c = 0; c < NLAB; ++c)
#pragma unroll
      for (int k = 0; k < 4; ++k) acc[c][k] = 0.f;
    for (int r = 0; r < 128; r += 4) {
      int lab[4];
      float xv[4][4];
#pragma unroll
      for (int q = 0; q < 4; ++q) {
        int row = r0 + r + q;
        lab[q] = labels[row];
        if (M == 0) {
          ushort4 u = *(const ushort4*)(en + (size_t)row * D_K + dbase + t * 4);
          xv[q][0] = bf16u_to_f(u.x); xv[q][1] = bf16u_to_f(u.y);
          xv[q][2] = bf16u_to_f(u.z); xv[q][3] = bf16u_to_f(u.w);
        } else {
          uchar4 u = *(const uchar4*)(e8 + (size_t)row * D_K + dbase + t * 4);
          xv[q][0] = dec8(u.x); xv[q][1] = dec8(u.y);
          xv[q][2] = dec8(u.z); xv[q][3] = dec8(u.w);
        }
      }
#pragma unroll
      for (int q = 0; q < 4; ++q)
#pragma unroll
        for (int c = 0; c < NLAB; ++c) {
          bool m = (lab[q] == c);
          acc[c][0] += m ? xv[q][0] : 0.f;
          acc[c][1] += m ? xv[q][1] : 0.f;
          acc[c][2] += m ? xv[q][2] : 0.f;
          acc[c][3] += m ? xv[q][3] : 0.f;
        }
    }
    float* dst = partial + (size_t)slab * (NLAB * D_K) + dbase;
#pragma unroll
    for (int c = 0; c < NLAB; ++c) {
      float4 v = {acc[c][0], acc[c][1], acc[c][2], acc[c][3]};
      *(float4*)(dst + c * D_K + t * 4) = v;
    }
  } else if (t >= 192 && half == 0) {
    int lane = t - 192;
    int cnt[NLAB];
#pragma unroll
    for (int c = 0; c < NLAB; ++c) cnt[c] = 0;
#pragma unroll
    for (int q = 0; q < 2; ++q) {
      int lab = labels[r0 + q * 64 + lane];
#pragma unroll
      for (int c = 0; c < NLAB; ++c) cnt[c] += (lab == c);
    }
#pragma unroll
    for (int c = 0; c < NLAB; ++c)
#pragma unroll
      for (int m = 1; m < 64; m <<= 1) cnt[c] += __shfl_xor(cnt[c], m);
    if (lane == 0)
#pragma unroll
      for (int c = 0; c < NLAB; ++c) atomicAdd(&hist[c], cnt[c]);
  }
}

// ---- node 3: exp-sum S-tiles via MX-scaled fp8 MFMA (16x16x128), upper-tri ----
// Blocks >= 2080 run class-sum stage B (only needs node-2 output).
// Ring-3 LDS (96KB -> 1 block/CU): prefetch(kc+2) issued each iteration,
// wait is counted vmcnt(8) (leave newest prefetch in flight; drain to 0 only
// at kc=5). Cover = 2 compute phases. Row swizzle as before: row r = 8 chunks
// of 16B, chunk c at slot (c+r)&7, applied on the GLOBAL source address
// (DMA dest stays wave-uniform base + lane*16).
__global__ __launch_bounds__(256) void k_scl(const unsigned char* __restrict__ e8,
                                             float* __restrict__ rse,
                                             const float* __restrict__ partial,
                                             float* __restrict__ T) {
  if (blockIdx.x >= 2080) {  // classumB role: T[idx] = sum_g partial[g][idx]
    int idx = (int)(blockIdx.x - 2080) * 256 + threadIdx.x;  // < 5376
    float v = 0.f;
    for (int g = 0; g < 64; ++g) v += partial[(size_t)g * (NLAB * D_K) + idx];
    T[idx] = v;
    return;
  }
  __shared__ __align__(16) unsigned char As[3][128 * 128];
  __shared__ __align__(16) unsigned char Bs[3][128 * 128];

  // supertile decode: 8x8-block supertiles over the triangle
  int rem = blockIdx.x;
  int BI = 0, BJ = 0;
  for (;;) {
    int sz = (BI == BJ) ? 36 : 64;
    if (rem < sz) break;
    rem -= sz;
    if (++BJ == 8) { ++BI; BJ = BI; }
  }
  int bi, bj;
  if (BI == BJ) {
    int r = 0, w = 8;
    while (rem >= w) { rem -= w; ++r; --w; }
    bi = BI * 8 + r;
    bj = BJ * 8 + r + rem;
  } else {
    bi = BI * 8 + (rem >> 3);
    bj = BJ * 8 + (rem & 7);
  }

  const int i0 = bi * 128, j0 = bj * 128;
  const int tid = threadIdx.x, wv = tid >> 6, lane = tid & 63;
  const int quad = lane >> 4, cix = lane & 15;
  const int rowTile = 64 * (wv >> 1), colTile = 64 * (wv & 1);

  // kc-invariant staging offsets (global source carries the swizzle)
  int aoff[4], boff[4], lbase[4];
#pragma unroll
  for (int it = 0; it < 4; ++it) {
    int s = it * 256 + tid;            // 16B slot in [0,1024)
    int r = s >> 3;                    // row 0..127
    int p = ((s & 7) - r) & 7;         // inverse of write swizzle
    aoff[it] = (i0 + r) * D_K + p * 16;
    boff[it] = (j0 + r) * D_K + p * 16;
    lbase[it] = (it * 256 + wv * 64) * 16;
  }

  f32x4 acc[4][4] = {};

  // prologue: prefetch kc=0 -> ring 0, kc=1 -> ring 1 (8+8 loads/wave)
#pragma unroll
  for (int it = 0; it < 4; ++it) {
    gl2lds16(e8 + (size_t)aoff[it], (char*)As[0] + lbase[it]);
    gl2lds16(e8 + (size_t)boff[it], (char*)Bs[0] + lbase[it]);
  }
#pragma unroll
  for (int it = 0; it < 4; ++it) {
    gl2lds16(e8 + (size_t)(aoff[it] + 128), (char*)As[1] + lbase[it]);
    gl2lds16(e8 + (size_t)(boff[it] + 128), (char*)Bs[1] + lbase[it]);
  }

#pragma unroll
  for (int kc = 0; kc < 6; ++kc) {
    const int cb = kc % 3;
    __builtin_amdgcn_sched_barrier(0);  // pin prior body (incl. MFMAs) above
    // wait prefetch(kc); keep prefetch(kc+1)'s 8 loads in flight (T4)
    if (kc < 5)
      asm volatile("s_waitcnt vmcnt(8)" ::: "memory");
    else
      asm volatile("s_waitcnt vmcnt(0)" ::: "memory");
    __builtin_amdgcn_s_barrier();
    asm volatile("" ::: "memory");
    if (kc < 4) {  // prefetch kc+2 into ring slot freed at barrier above
      const int nb = (kc + 2) % 3;
#pragma unroll
      for (int it = 0; it < 4; ++it) {
        gl2lds16(e8 + (size_t)(aoff[it] + (kc + 2) * 128), (char*)As[nb] + lbase[it]);
        gl2lds16(e8 + (size_t)(boff[it] + (kc + 2) * 128), (char*)Bs[nb] + lbase[it]);
      }
    }
    asm volatile("" ::: "memory");
    i32x8 aF[4];
#pragma unroll
    for (int mt = 0; mt < 4; ++mt) {
      int r = rowTile + 16 * mt + cix;
      const char* base = (const char*)As[cb] + r * 128;
      int4 lo = *(const int4*)(base + (((quad * 2 + 0) + r) & 7) * 16);
      int4 hi = *(const int4*)(base + (((quad * 2 + 1) + r) & 7) * 16);
      aF[mt][0] = lo.x; aF[mt][1] = lo.y; aF[mt][2] = lo.z; aF[mt][3] = lo.w;
      aF[mt][4] = hi.x; aF[mt][5] = hi.y; aF[mt][6] = hi.z; aF[mt][7] = hi.w;
    }
#pragma unroll
    for (int nt = 0; nt < 4; ++nt) {  // bF streamed: 1 live frag
      int r = colTile + 16 * nt + cix;
      const char* base = (const char*)Bs[cb] + r * 128;
      int4 lo = *(const int4*)(base + (((quad * 2 + 0) + r) & 7) * 16);
      int4 hi = *(const int4*)(base + (((quad * 2 + 1) + r) & 7) * 16);
      i32x8 bF;
      bF[0] = lo.x; bF[1] = lo.y; bF[2] = lo.z; bF[3] = lo.w;
      bF[4] = hi.x; bF[5] = hi.y; bF[6] = hi.z; bF[7] = hi.w;
#pragma unroll
      for (int mt = 0; mt < 4; ++mt)
        acc[mt][nt] = __builtin_amdgcn_mfma_scale_f32_16x16x128_f8f6f4(
            aF[mt], bF, acc[mt][nt], 0, 0, 0, 127, 0, 127);  // fp8 fmt, scale=1.0
    }
  }

  // ---- epilogue: exp-sums only (16x16 C/D: col=lane&15, row=quad*4+rg) ----
  if (bi != bj) {
    float ce_col[4] = {0.f, 0.f, 0.f, 0.f};
#pragma unroll
    for (int mt = 0; mt < 4; ++mt) {
      int rowbase = i0 + rowTile + 16 * mt + quad * 4;
      float rs_e[4] = {0.f, 0.f, 0.f, 0.f};
#pragma unroll
      for (int nt = 0; nt < 4; ++nt) {
#pragma unroll
        for (int rg = 0; rg < 4; ++rg) {
          float e = __expf(acc[mt][nt][rg] - MBOUND);
          rs_e[rg] += e;
          ce_col[nt] += e;
        }
      }
#pragma unroll
      for (int rg = 0; rg < 4; ++rg)
#pragma unroll
        for (int m = 1; m <= 8; m <<= 1) rs_e[rg] += __shfl_xor(rs_e[rg], m);
      if (cix == 0)
#pragma unroll
        for (int rg = 0; rg < 4; ++rg) atomicAdd(&rse[rowbase + rg], rs_e[rg]);
    }
#pragma unroll
    for (int nt = 0; nt < 4; ++nt) {
      ce_col[nt] += __shfl_xor(ce_col[nt], 16);
      ce_col[nt] += __shfl_xor(ce_col[nt], 32);
    }
    if (quad == 0)
#pragma unroll
      for (int nt = 0; nt < 4; ++nt)
        atomicAdd(&rse[j0 + colTile + 16 * nt + cix], ce_col[nt]);
  } else {
#pragma unroll
    for (int mt = 0; mt < 4; ++mt) {
      int rowbase = i0 + rowTile + 16 * mt + quad * 4;
      float rs_e[4] = {0.f, 0.f, 0.f, 0.f};
#pragma unroll
      for (int nt = 0; nt < 4; ++nt) {
        int gcol = j0 + colTile + 16 * nt + cix;
#pragma unroll
        for (int rg = 0; rg < 4; ++rg) {
          bool dg = (rowbase + rg) == gcol;
          rs_e[rg] += dg ? 0.f : __expf(acc[mt][nt][rg] - MBOUND);
        }
      }
#pragma unroll
      for (int rg = 0; rg < 4; ++rg)
#pragma unroll
        for (int m = 1; m <= 8; m <<= 1) rs_e[rg] += __shfl_xor(rs_e[rg], m);
      if (cix == 0)
#pragma unroll
        for (int rg = 0; rg < 4; ++rg) atomicAdd(&rse[rowbase + rg], rs_e[rg]);
    }
  }
}

// ---- node 4: per-row combine + last-block final reduce ----
template <int M>
__global__ __launch_bounds__(256) void k_rowfinal(
    const float* __restrict__ rse, const unsigned short* __restrict__ en,
    const unsigned char* __restrict__ e8, const float* __restrict__ T,
    const int* __restrict__ labels, const int* __restrict__ hist,
    const float* __restrict__ celoss, float* __restrict__ contrP,
    int* __restrict__ done_count, float* __restrict__ out) {
  __shared__ float part[4];
  int wv = threadIdx.x >> 6, lane = threadIdx.x & 63;
  int row = blockIdx.x * 4 + wv;
  int l = labels[row];
  const float4* t4 = (const float4*)(T + (size_t)l * D_K);
  float pd = 0.f, sd = 0.f;
#pragma unroll
  for (int j = 0; j < 3; ++j) {
    float a0, a1, a2, a3;
    if (M == 0) {
      ushort4 u = ((const ushort4*)(en + (size_t)row * D_K))[j * 64 + lane];
      a0 = bf16u_to_f(u.x); a1 = bf16u_to_f(u.y);
      a2 = bf16u_to_f(u.z); a3 = bf16u_to_f(u.w);
    } else {
      uint u = ((const uint*)(e8 + (size_t)row * D_K))[j * 64 + lane];
      a0 = dec8(u & 0xff); a1 = dec8((u >> 8) & 0xff);
      a2 = dec8((u >> 16) & 0xff); a3 = dec8(u >> 24);
    }
    float4 t = t4[j * 64 + lane];
    pd += a0 * t.x + a1 * t.y + a2 * t.z + a3 * t.w;
    sd += a0 * a0 + a1 * a1 + a2 * a2 + a3 * a3;
  }
#pragma unroll
  for (int m = 1; m < 64; m <<= 1) {
    pd += __shfl_xor(pd, m);
    sd += __shfl_xor(sd, m);
  }
  if (lane == 0) {
    int ni = hist[l] - 1;
    float per = 0.f;
    if (ni > 0) per = MBOUND + __logf(rse[row]) - (pd - sd) / (float)ni;
    part[wv] = 0.9f * per + (0.1f / (float)B_N) * celoss[row];
  }
  __syncthreads();
  if (threadIdx.x == 0) {
    float v = part[0] + part[1] + part[2] + part[3];
    atomicAdd(&contrP[(blockIdx.x & 63) * 16], v);
    __threadfence();
    int n = atomicAdd(done_count, 1);
    if (n == (int)gridDim.x - 1) {
      float s = 0.f;
      for (int i = 0; i < 64; ++i)
        s += __hip_atomic_load(&contrP[i * 16], __ATOMIC_RELAXED,
                               __HIP_MEMORY_SCOPE_AGENT);
      out[0] = s;
    }
  }
}

extern "C" void kernel_launch(void* const* d_in, const int* in_sizes, int n_in,
                              void* d_out, int out_size, void* d_ws, size_t ws_size,
                              hipStream_t stream) {
  const float* cls    = (const float*)d_in[0];
  const float* pooled = (const float*)d_in[1];
  const int*   labels = (const int*)d_in[2];
  const float* W      = (const float*)d_in[3];
  const float* bias   = (const float*)d_in[4];
  float* out = (float*)d_out;

  char* ws = (char*)d_ws;
  unsigned char* e8 = (unsigned char*)ws;          // 6291456 B
  const size_t EN_B = (size_t)B_N * D_K * 2;       // 12582912
  const size_t E8_B = (size_t)B_N * D_K;           // 6291456
  size_t need_big = E8_B + EN_B + 98304 + 64 * (size_t)(NLAB * D_K) * 4;
  bool big = ws_size >= need_big;                  // 20348928 B
  unsigned short* en = (unsigned short*)(ws + E8_B);
  size_t off = big ? (E8_B + EN_B) : E8_B;
  float* rse     = (float*)(ws + off);             // +0      (32768) [zeroed]
  int*   hist    = (int*)(ws + off + 32768);       // +32768  (128)   [zeroed]
  int*   done    = (int*)(ws + off + 32896);       // +32896  (128)   [zeroed]
  float* contrP  = (float*)(ws + off + 33024);     // +33024  (4096)  [zeroed]
  float* T       = (float*)(ws + off + 37120);     // +37120  (21504, fully written)
  float* celoss  = (float*)(ws + off + 58624);     // +58624  (32768, fully written)
  float* partial = (float*)(ws + off + 98304);     // +98304  (1376256, fully written)
  int*   zr      = (int*)(ws + off);               // 9280 ints = rse..contrP

  if (big)
    k_prep<1><<<B_N / 4, 256, 0, stream>>>(cls, pooled, labels, W, bias, e8, en,
                                           out + 1, celoss, zr);
  else
    k_prep<0><<<B_N / 4, 256, 0, stream>>>(cls, pooled, labels, W, bias, e8, en,
                                           out + 1, celoss, zr);
  if (big)
    k_classumA<0><<<128, 256, 0, stream>>>(en, e8, labels, partial, hist);
  else
    k_classumA<1><<<128, 256, 0, stream>>>(en, e8, labels, partial, hist);
  k_scl<<<2101, 256, 0, stream>>>(e8, rse, partial, T);  // +21 classumB blocks
  if (big)
    k_rowfinal<0><<<B_N / 4, 256, 0, stream>>>(rse, en, e8, T, labels, hist,
                                               celoss, contrP, done, out);
  else
    k_rowfinal<1><<<B_N / 4, 256, 0, stream>>>(rse, en, e8, T, labels, hist,
                                               celoss, contrP, done, out);
}

// Round 4
// 213.098 us; speedup vs baseline: 1.3610x; 1.1516x over previous
//
#include <hip/hip_runtime.h>
#include <hip/hip_bf16.h>

// BERT_SCL: loss = 0.9 * supcon(cls_emb, labels) + 0.1 * CE(pooled@W.T + b, labels)
// d_out[0] = loss, d_out[1..57344] = logits (8192 x 7, f32)
//
// e8 = fp8_e4m3(row-normalized cls * 1/sqrt(TEMP)); en = bf16 of the same.
// S_ij = e8_i . e8_j <= M = 1/TEMP -> fixed-max logsumexp. possum_i =
// en_i.T_{l_i} - ||en_i||^2 (positive mask linear in S) -> big kernel does
// ONLY exp-sums, via MX-scaled fp8 MFMA (16x16x128, unit scales 0x7F).
// S symmetric -> tiles bi <= bj (2080); off-diag tiles emit row AND col sums.
//
// Ledger: r2 single-address atomics ~100us; r3 supertile fixes L2 thrash;
// r4 forced waves/EU -> acc spill = never force; r5 <1blk/CU latency-bound;
// r6 k_scl staging/latency-bound; r7 scaled MFMA + rotate swizzle + dual
// e8+bf16; r8 node count weak lever; r9 dbuf+raw-barrier 81->64.5us;
// r10 direct-from-L2 FAILED 129us (strided frag gathers = request-rate
// bound -> LDS staging mandatory); r11 ring-3 @1blk/CU FAILED 82us
// (occupancy 9.8%: TLP beats pipeline depth -> r5 rule reconfirmed).
// r12 (this): back to r9 structure (dbuf 64KB, 2 blk/CU, vmcnt(0)) +
// (a) T1 XCD-bijective tile swizzle: FETCH was 25MB = 4x array (consecutive
//     bids round-robin XCDs -> per-XCD set spans 8 supertiles >> 4MB L2;
//     ~6% stage lines miss to HBM ~900cy, and vmcnt(0)+barrier waits the
//     slowest line EVERY kc). tile=(bid%8)*260+bid/8 (2080%8==0, bijective)
//     -> each XCD walks ~1 supertile window = 1.57MB, L2-resident.
// (b) T5 setprio(1) around MFMA cluster (2 independent-phase blocks/CU =
//     attn-like regime, m191 +4-7%).
// (c) rowfinal final-reduce parallelized (was 1 thread x 64 device-scope
//     loads ~13us serial tail).

#define B_N 8192
#define D_K 768
#define NLAB 7
#define MBOUND 3.3333333333333335f /* 1/TEMP */
#define RTINV 1.8257418583505538f  /* 1/sqrt(TEMP) */

typedef float f32x4 __attribute__((ext_vector_type(4)));
typedef int i32x8 __attribute__((ext_vector_type(8)));

__device__ __forceinline__ void gl2lds16(const void* g, void* l) {
  __builtin_amdgcn_global_load_lds(
      (const __attribute__((address_space(1))) void*)g,
      (__attribute__((address_space(3))) void*)l, 16, 0, 0);
}

__device__ __forceinline__ float bf16u_to_f(unsigned short u) {
  return __uint_as_float(((unsigned int)u) << 16);
}

// exact fp8 e4m3fn -> f32 decode (fallback paths only)
__device__ __forceinline__ float dec8(unsigned int b) {
  unsigned int s = (b >> 7) & 1u, e = (b >> 3) & 15u, m = b & 7u;
  float fn = __uint_as_float((s << 31) | ((e + 120u) << 23) | (m << 20));
  float fs = (s ? -1.f : 1.f) * (float)m * 0.001953125f;
  return e ? fn : fs;
}

// ---- node 1: k_prep = zero accumulators + normalize -> {fp8, bf16} + logits + CE ----
template <int WBF>
__global__ __launch_bounds__(256) void k_prep(
    const float* __restrict__ cls, const float* __restrict__ pooled,
    const int* __restrict__ labels, const float* __restrict__ W,
    const float* __restrict__ bias, unsigned char* __restrict__ e8,
    unsigned short* __restrict__ en, float* __restrict__ logits_out,
    float* __restrict__ celoss, int* __restrict__ zr) {
  if (blockIdx.x == 0)
    for (int t = threadIdx.x; t < 9280; t += 256) zr[t] = 0;

  int wv = threadIdx.x >> 6, lane = threadIdx.x & 63;
  int row = blockIdx.x * 4 + wv;

  // --- normalize + quantize ---
  const float4* src = (const float4*)(cls + (size_t)row * D_K);
  float4 x[3];
  float ss = 0.f;
#pragma unroll
  for (int j = 0; j < 3; ++j) {
    x[j] = src[j * 64 + lane];
    ss += x[j].x * x[j].x + x[j].y * x[j].y + x[j].z * x[j].z + x[j].w * x[j].w;
  }
#pragma unroll
  for (int m = 1; m < 64; m <<= 1) ss += __shfl_xor(ss, m);
  float sc = rsqrtf(ss) * RTINV;
  int* d8 = (int*)(e8 + (size_t)row * D_K);
  ushort4* db = (ushort4*)(en + (size_t)row * D_K);
#pragma unroll
  for (int j = 0; j < 3; ++j) {
    int w32 = __builtin_amdgcn_cvt_pk_fp8_f32(x[j].x * sc, x[j].y * sc, 0, false);
    w32 = __builtin_amdgcn_cvt_pk_fp8_f32(x[j].z * sc, x[j].w * sc, w32, true);
    d8[j * 64 + lane] = w32;
    if (WBF) {
      const float* xv = reinterpret_cast<const float*>(&x[j]);
      ushort4 o;
      unsigned short* ov = reinterpret_cast<unsigned short*>(&o);
#pragma unroll
      for (int k = 0; k < 4; ++k) {
        __hip_bfloat16 h = __float2bfloat16(xv[k] * sc);
        ov[k] = *reinterpret_cast<unsigned short*>(&h);
      }
      db[j * 64 + lane] = o;
    }
  }

  // --- logits + CE ---
  const float4* p4 = (const float4*)(pooled + (size_t)row * D_K);
  float acc[NLAB];
#pragma unroll
  for (int c = 0; c < NLAB; ++c) acc[c] = 0.f;
#pragma unroll
  for (int j = 0; j < 3; ++j) {
    float4 xx = p4[j * 64 + lane];
#pragma unroll
    for (int c = 0; c < NLAB; ++c) {
      float4 w = ((const float4*)(W + c * D_K))[j * 64 + lane];
      acc[c] += xx.x * w.x + xx.y * w.y + xx.z * w.z + xx.w * w.w;
    }
  }
#pragma unroll
  for (int c = 0; c < NLAB; ++c)
#pragma unroll
    for (int m = 1; m < 64; m <<= 1) acc[c] += __shfl_xor(acc[c], m);
  if (lane == 0) {
    float l[NLAB], mx = -1e30f;
#pragma unroll
    for (int c = 0; c < NLAB; ++c) { l[c] = acc[c] + bias[c]; mx = fmaxf(mx, l[c]); }
    float se = 0.f;
#pragma unroll
    for (int c = 0; c < NLAB; ++c) se += __expf(l[c] - mx);
    float lse = mx + __logf(se);
    celoss[row] = lse - l[labels[row]];
    float* o = logits_out + (size_t)row * NLAB;
#pragma unroll
    for (int c = 0; c < NLAB; ++c) o[c] = l[c];
  }
}

// ---- node 2: class-sum stage A (direct stores) + hist ----
// 128 blocks: block g = (slab g>>1, dim-half g&1). Each block sums 384 dims of
// its slab's 128 rows; same partial layout (bitwise-identical sums). hist by
// wave 3 of half==0 blocks. M=0: read bf16 en; M=1: read fp8 e8 (fallback).
template <int M>
__global__ __launch_bounds__(256) void k_classumA(
    const unsigned short* __restrict__ en, const unsigned char* __restrict__ e8,
    const int* __restrict__ labels, float* __restrict__ partial,
    int* __restrict__ hist) {
  int g = blockIdx.x, t = threadIdx.x;
  int slab = g >> 1, half = g & 1;
  int r0 = slab * 128;
  int dbase = half * 384;
  if (t < 96) {
    float acc[NLAB][4];
#pragma unroll
    for (int c = 0; c < NLAB; ++c)
#pragma unroll
      for (int k = 0; k < 4; ++k) acc[c][k] = 0.f;
    for (int r = 0; r < 128; r += 4) {
      int lab[4];
      float xv[4][4];
#pragma unroll
      for (int q = 0; q < 4; ++q) {
        int row = r0 + r + q;
        lab[q] = labels[row];
        if (M == 0) {
          ushort4 u = *(const ushort4*)(en + (size_t)row * D_K + dbase + t * 4);
          xv[q][0] = bf16u_to_f(u.x); xv[q][1] = bf16u_to_f(u.y);
          xv[q][2] = bf16u_to_f(u.z); xv[q][3] = bf16u_to_f(u.w);
        } else {
          uchar4 u = *(const uchar4*)(e8 + (size_t)row * D_K + dbase + t * 4);
          xv[q][0] = dec8(u.x); xv[q][1] = dec8(u.y);
          xv[q][2] = dec8(u.z); xv[q][3] = dec8(u.w);
        }
      }
#pragma unroll
      for (int q = 0; q < 4; ++q)
#pragma unroll
        for (int c = 0; c < NLAB; ++c) {
          bool m = (lab[q] == c);
          acc[c][0] += m ? xv[q][0] : 0.f;
          acc[c][1] += m ? xv[q][1] : 0.f;
          acc[c][2] += m ? xv[q][2] : 0.f;
          acc[c][3] += m ? xv[q][3] : 0.f;
        }
    }
    float* dst = partial + (size_t)slab * (NLAB * D_K) + dbase;
#pragma unroll
    for (int c = 0; c < NLAB; ++c) {
      float4 v = {acc[c][0], acc[c][1], acc[c][2], acc[c][3]};
      *(float4*)(dst + c * D_K + t * 4) = v;
    }
  } else if (t >= 192 && half == 0) {
    int lane = t - 192;
    int cnt[NLAB];
#pragma unroll
    for (int c = 0; c < NLAB; ++c) cnt[c] = 0;
#pragma unroll
    for (int q = 0; q < 2; ++q) {
      int lab = labels[r0 + q * 64 + lane];
#pragma unroll
      for (int c = 0; c < NLAB; ++c) cnt[c] += (lab == c);
    }
#pragma unroll
    for (int c = 0; c < NLAB; ++c)
#pragma unroll
      for (int m = 1; m < 64; m <<= 1) cnt[c] += __shfl_xor(cnt[c], m);
    if (lane == 0)
#pragma unroll
      for (int c = 0; c < NLAB; ++c) atomicAdd(&hist[c], cnt[c]);
  }
}

// ---- node 3: exp-sum S-tiles via MX-scaled fp8 MFMA (16x16x128), upper-tri ----
// Blocks >= 2080 run class-sum stage B. Triangle blocks: XCD-bijective remap
// tile=(bid%8)*260+bid/8 so each XCD walks a contiguous supertile range
// (instantaneous window ~1 supertile = 1.57MB, L2-resident). Double-buffered
// LDS (64KB, 2 blk/CU): per kc {sched_barrier; vmcnt(0); s_barrier; issue
// prefetch(kc+1); frag ds_reads; setprio(1) MFMAs setprio(0)}. Row swizzle:
// row r = 8 chunks of 16B, chunk c at slot (c+r)&7, applied on the GLOBAL
// source address (DMA dest stays wave-uniform base + lane*16).
__global__ __launch_bounds__(256) void k_scl(const unsigned char* __restrict__ e8,
                                             float* __restrict__ rse,
                                             const float* __restrict__ partial,
                                             float* __restrict__ T) {
  if (blockIdx.x >= 2080) {  // classumB role: T[idx] = sum_g partial[g][idx]
    int idx = (int)(blockIdx.x - 2080) * 256 + threadIdx.x;  // < 5376
    float v = 0.f;
    for (int g = 0; g < 64; ++g) v += partial[(size_t)g * (NLAB * D_K) + idx];
    T[idx] = v;
    return;
  }
  __shared__ __align__(16) unsigned char As[2][128 * 128];
  __shared__ __align__(16) unsigned char Bs[2][128 * 128];

  // T1: XCD-bijective swizzle (2080 = 8 * 260 exactly)
  int orig = blockIdx.x;
  int rem = (orig & 7) * 260 + (orig >> 3);

  // supertile decode: 8x8-block supertiles over the triangle
  int BI = 0, BJ = 0;
  for (;;) {
    int sz = (BI == BJ) ? 36 : 64;
    if (rem < sz) break;
    rem -= sz;
    if (++BJ == 8) { ++BI; BJ = BI; }
  }
  int bi, bj;
  if (BI == BJ) {
    int r = 0, w = 8;
    while (rem >= w) { rem -= w; ++r; --w; }
    bi = BI * 8 + r;
    bj = BJ * 8 + r + rem;
  } else {
    bi = BI * 8 + (rem >> 3);
    bj = BJ * 8 + (rem & 7);
  }

  const int i0 = bi * 128, j0 = bj * 128;
  const int tid = threadIdx.x, wv = tid >> 6, lane = tid & 63;
  const int quad = lane >> 4, cix = lane & 15;
  const int rowTile = 64 * (wv >> 1), colTile = 64 * (wv & 1);

  // kc-invariant staging offsets (global source carries the swizzle)
  int aoff[4], boff[4], lbase[4];
#pragma unroll
  for (int it = 0; it < 4; ++it) {
    int s = it * 256 + tid;            // 16B slot in [0,1024)
    int r = s >> 3;                    // row 0..127
    int p = ((s & 7) - r) & 7;         // inverse of write swizzle
    aoff[it] = (i0 + r) * D_K + p * 16;
    boff[it] = (j0 + r) * D_K + p * 16;
    lbase[it] = (it * 256 + wv * 64) * 16;
  }

  f32x4 acc[4][4] = {};

  // prologue: prefetch kc=0 into buffer 0
#pragma unroll
  for (int it = 0; it < 4; ++it) {
    gl2lds16(e8 + (size_t)aoff[it], (char*)As[0] + lbase[it]);
    gl2lds16(e8 + (size_t)boff[it], (char*)Bs[0] + lbase[it]);
  }

#pragma unroll
  for (int kc = 0; kc < 6; ++kc) {
    const int cb = kc & 1;
    __builtin_amdgcn_sched_barrier(0);  // pin prior body (incl. MFMAs) above
    asm volatile("s_waitcnt vmcnt(0)" ::: "memory");  // prefetch(kc) landed
    __builtin_amdgcn_s_barrier();
    asm volatile("" ::: "memory");
    if (kc < 5) {  // prefetch kc+1 into other buffer; rides under compute
#pragma unroll
      for (int it = 0; it < 4; ++it) {
        gl2lds16(e8 + (size_t)(aoff[it] + (kc + 1) * 128), (char*)As[cb ^ 1] + lbase[it]);
        gl2lds16(e8 + (size_t)(boff[it] + (kc + 1) * 128), (char*)Bs[cb ^ 1] + lbase[it]);
      }
    }
    asm volatile("" ::: "memory");
    i32x8 aF[4];
#pragma unroll
    for (int mt = 0; mt < 4; ++mt) {
      int r = rowTile + 16 * mt + cix;
      const char* base = (const char*)As[cb] + r * 128;
      int4 lo = *(const int4*)(base + (((quad * 2 + 0) + r) & 7) * 16);
      int4 hi = *(const int4*)(base + (((quad * 2 + 1) + r) & 7) * 16);
      aF[mt][0] = lo.x; aF[mt][1] = lo.y; aF[mt][2] = lo.z; aF[mt][3] = lo.w;
      aF[mt][4] = hi.x; aF[mt][5] = hi.y; aF[mt][6] = hi.z; aF[mt][7] = hi.w;
    }
    __builtin_amdgcn_s_setprio(1);  // T5: favor MFMA-phase block on the CU
#pragma unroll
    for (int nt = 0; nt < 4; ++nt) {  // bF streamed: 1 live frag
      int r = colTile + 16 * nt + cix;
      const char* base = (const char*)Bs[cb] + r * 128;
      int4 lo = *(const int4*)(base + (((quad * 2 + 0) + r) & 7) * 16);
      int4 hi = *(const int4*)(base + (((quad * 2 + 1) + r) & 7) * 16);
      i32x8 bF;
      bF[0] = lo.x; bF[1] = lo.y; bF[2] = lo.z; bF[3] = lo.w;
      bF[4] = hi.x; bF[5] = hi.y; bF[6] = hi.z; bF[7] = hi.w;
#pragma unroll
      for (int mt = 0; mt < 4; ++mt)
        acc[mt][nt] = __builtin_amdgcn_mfma_scale_f32_16x16x128_f8f6f4(
            aF[mt], bF, acc[mt][nt], 0, 0, 0, 127, 0, 127);  // fp8 fmt, scale=1.0
    }
    __builtin_amdgcn_s_setprio(0);
  }

  // ---- epilogue: exp-sums only (16x16 C/D: col=lane&15, row=quad*4+rg) ----
  if (bi != bj) {
    float ce_col[4] = {0.f, 0.f, 0.f, 0.f};
#pragma unroll
    for (int mt = 0; mt < 4; ++mt) {
      int rowbase = i0 + rowTile + 16 * mt + quad * 4;
      float rs_e[4] = {0.f, 0.f, 0.f, 0.f};
#pragma unroll
      for (int nt = 0; nt < 4; ++nt) {
#pragma unroll
        for (int rg = 0; rg < 4; ++rg) {
          float e = __expf(acc[mt][nt][rg] - MBOUND);
          rs_e[rg] += e;
          ce_col[nt] += e;
        }
      }
#pragma unroll
      for (int rg = 0; rg < 4; ++rg)
#pragma unroll
        for (int m = 1; m <= 8; m <<= 1) rs_e[rg] += __shfl_xor(rs_e[rg], m);
      if (cix == 0)
#pragma unroll
        for (int rg = 0; rg < 4; ++rg) atomicAdd(&rse[rowbase + rg], rs_e[rg]);
    }
#pragma unroll
    for (int nt = 0; nt < 4; ++nt) {
      ce_col[nt] += __shfl_xor(ce_col[nt], 16);
      ce_col[nt] += __shfl_xor(ce_col[nt], 32);
    }
    if (quad == 0)
#pragma unroll
      for (int nt = 0; nt < 4; ++nt)
        atomicAdd(&rse[j0 + colTile + 16 * nt + cix], ce_col[nt]);
  } else {
#pragma unroll
    for (int mt = 0; mt < 4; ++mt) {
      int rowbase = i0 + rowTile + 16 * mt + quad * 4;
      float rs_e[4] = {0.f, 0.f, 0.f, 0.f};
#pragma unroll
      for (int nt = 0; nt < 4; ++nt) {
        int gcol = j0 + colTile + 16 * nt + cix;
#pragma unroll
        for (int rg = 0; rg < 4; ++rg) {
          bool dg = (rowbase + rg) == gcol;
          rs_e[rg] += dg ? 0.f : __expf(acc[mt][nt][rg] - MBOUND);
        }
      }
#pragma unroll
      for (int rg = 0; rg < 4; ++rg)
#pragma unroll
        for (int m = 1; m <= 8; m <<= 1) rs_e[rg] += __shfl_xor(rs_e[rg], m);
      if (cix == 0)
#pragma unroll
        for (int rg = 0; rg < 4; ++rg) atomicAdd(&rse[rowbase + rg], rs_e[rg]);
    }
  }
}

// ---- node 4: per-row combine + last-block final reduce (parallel) ----
template <int M>
__global__ __launch_bounds__(256) void k_rowfinal(
    const float* __restrict__ rse, const unsigned short* __restrict__ en,
    const unsigned char* __restrict__ e8, const float* __restrict__ T,
    const int* __restrict__ labels, const int* __restrict__ hist,
    const float* __restrict__ celoss, float* __restrict__ contrP,
    int* __restrict__ done_count, float* __restrict__ out) {
  __shared__ float part[4];
  __shared__ int is_last;
  int wv = threadIdx.x >> 6, lane = threadIdx.x & 63;
  int row = blockIdx.x * 4 + wv;
  int l = labels[row];
  const float4* t4 = (const float4*)(T + (size_t)l * D_K);
  float pd = 0.f, sd = 0.f;
#pragma unroll
  for (int j = 0; j < 3; ++j) {
    float a0, a1, a2, a3;
    if (M == 0) {
      ushort4 u = ((const ushort4*)(en + (size_t)row * D_K))[j * 64 + lane];
      a0 = bf16u_to_f(u.x); a1 = bf16u_to_f(u.y);
      a2 = bf16u_to_f(u.z); a3 = bf16u_to_f(u.w);
    } else {
      uint u = ((const uint*)(e8 + (size_t)row * D_K))[j * 64 + lane];
      a0 = dec8(u & 0xff); a1 = dec8((u >> 8) & 0xff);
      a2 = dec8((u >> 16) & 0xff); a3 = dec8(u >> 24);
    }
    float4 t = t4[j * 64 + lane];
    pd += a0 * t.x + a1 * t.y + a2 * t.z + a3 * t.w;
    sd += a0 * a0 + a1 * a1 + a2 * a2 + a3 * a3;
  }
#pragma unroll
  for (int m = 1; m < 64; m <<= 1) {
    pd += __shfl_xor(pd, m);
    sd += __shfl_xor(sd, m);
  }
  if (lane == 0) {
    int ni = hist[l] - 1;
    float per = 0.f;
    if (ni > 0) per = MBOUND + __logf(rse[row]) - (pd - sd) / (float)ni;
    part[wv] = 0.9f * per + (0.1f / (float)B_N) * celoss[row];
  }
  __syncthreads();
  if (threadIdx.x == 0) {
    float v = part[0] + part[1] + part[2] + part[3];
    atomicAdd(&contrP[(blockIdx.x & 63) * 16], v);
    __threadfence();
    int n = atomicAdd(done_count, 1);
    is_last = (n == (int)gridDim.x - 1) ? 1 : 0;
  }
  __syncthreads();
  if (is_last && threadIdx.x < 64) {
    float s = __hip_atomic_load(&contrP[threadIdx.x * 16], __ATOMIC_RELAXED,
                                __HIP_MEMORY_SCOPE_AGENT);
#pragma unroll
    for (int m = 1; m < 64; m <<= 1) s += __shfl_xor(s, m);
    if (threadIdx.x == 0) out[0] = s;
  }
}

extern "C" void kernel_launch(void* const* d_in, const int* in_sizes, int n_in,
                              void* d_out, int out_size, void* d_ws, size_t ws_size,
                              hipStream_t stream) {
  const float* cls    = (const float*)d_in[0];
  const float* pooled = (const float*)d_in[1];
  const int*   labels = (const int*)d_in[2];
  const float* W      = (const float*)d_in[3];
  const float* bias   = (const float*)d_in[4];
  float* out = (float*)d_out;

  char* ws = (char*)d_ws;
  unsigned char* e8 = (unsigned char*)ws;          // 6291456 B
  const size_t EN_B = (size_t)B_N * D_K * 2;       // 12582912
  const size_t E8_B = (size_t)B_N * D_K;           // 6291456
  size_t need_big = E8_B + EN_B + 98304 + 64 * (size_t)(NLAB * D_K) * 4;
  bool big = ws_size >= need_big;                  // 20348928 B
  unsigned short* en = (unsigned short*)(ws + E8_B);
  size_t off = big ? (E8_B + EN_B) : E8_B;
  float* rse     = (float*)(ws + off);             // +0      (32768) [zeroed]
  int*   hist    = (int*)(ws + off + 32768);       // +32768  (128)   [zeroed]
  int*   done    = (int*)(ws + off + 32896);       // +32896  (128)   [zeroed]
  float* contrP  = (float*)(ws + off + 33024);     // +33024  (4096)  [zeroed]
  float* T       = (float*)(ws + off + 37120);     // +37120  (21504, fully written)
  float* celoss  = (float*)(ws + off + 58624);     // +58624  (32768, fully written)
  float* partial = (float*)(ws + off + 98304);     // +98304  (1376256, fully written)
  int*   zr      = (int*)(ws + off);               // 9280 ints = rse..contrP

  if (big)
    k_prep<1><<<B_N / 4, 256, 0, stream>>>(cls, pooled, labels, W, bias, e8, en,
                                           out + 1, celoss, zr);
  else
    k_prep<0><<<B_N / 4, 256, 0, stream>>>(cls, pooled, labels, W, bias, e8, en,
                                           out + 1, celoss, zr);
  if (big)
    k_classumA<0><<<128, 256, 0, stream>>>(en, e8, labels, partial, hist);
  else
    k_classumA<1><<<128, 256, 0, stream>>>(en, e8, labels, partial, hist);
  k_scl<<<2101, 256, 0, stream>>>(e8, rse, partial, T);  // +21 classumB blocks
  if (big)
    k_rowfinal<0><<<B_N / 4, 256, 0, stream>>>(rse, en, e8, T, labels, hist,
                                               celoss, contrP, done, out);
  else
    k_rowfinal<1><<<B_N / 4, 256, 0, stream>>>(rse, en, e8, T, labels, hist,
                                               celoss, contrP, done, out);
}